// Round 5
// baseline (840.448 us; speedup 1.0000x reference)
//
#include <hip/hip_runtime.h>
#include <hip/hip_bf16.h>
#include <math.h>

#define NN 100000
#define NE 1000000
#define NG 2048
#define FIN 78
#define DD 32
#define TD 208
#define H1 170
#define H2 128
#define BN_EPS 1e-5f
#define SCAN_BLK 1024
#define NB_SCAN ((NN + SCAN_BLK - 1) / SCAN_BLK)   // 98
#define NCHUNK (NN / 16)                           // 6250 (NN % 16 == 0)

typedef __hip_bfloat16 bf16;
typedef unsigned int uint;
__device__ __forceinline__ float b2f(bf16 v) { return __bfloat162float(v); }
__device__ __forceinline__ float lo2f(uint v) { return __uint_as_float(v << 16); }
__device__ __forceinline__ float hi2f(uint v) { return __uint_as_float(v & 0xffff0000u); }
__device__ __forceinline__ uint packbf(float a, float b) {
    __hip_bfloat162 h;
    h.x = __float2bfloat16(a);
    h.y = __float2bfloat16(b);
    return *reinterpret_cast<uint*>(&h);
}

// ---- static device workspace (module memory; fully rewritten every call) ----
__device__ uint  g_y16[NN * 16];    // layer-1 pre-agg features, bf16-pairs (64 B rows)
__device__ uint  g_za[NN * 16];     // z ping buffer (layer1 out, layer3 out), bf16-pairs
__device__ uint  g_zb[NN * 16];     // z pong buffer (layer2 out), bf16-pairs
__device__ float g_sum[DD];         // BN stat accumulators
__device__ float g_sq[DD];
__device__ float g_m[DD];           // BN mean / inv-std of last computed layer
__device__ float g_inv[DD];
__device__ float g_Wp[DD * DD];     // BN-folded next-layer weight: diag(inv) @ W
__device__ float g_c[DD];           // (m*inv) @ W  (subtract per node per (deg+1))
__device__ float g_tm[TD];          // target BN mean
__device__ float g_ta[TD];          // target BN inv*gamma
// CSR-by-dst build
__device__ int g_deg[NN];
__device__ int g_tmp[NN];
__device__ int g_bsum[NB_SCAN];
__device__ int g_bpre[NB_SCAN];
__device__ int g_rowptr[NN + 1];
__device__ int g_cur[NN + 1];
__device__ int g_srcs[NE];

__global__ void k_zero() {
    int i = blockIdx.x * blockDim.x + threadIdx.x;
    int stride = gridDim.x * blockDim.x;
    for (int j = i; j < NN; j += stride) g_deg[j] = 0;
    if (i < DD) { g_sum[i] = 0.f; g_sq[i] = 0.f; }
}

// ---------------- CSR build (by destination) ----------------
__global__ void k_hist(const int* __restrict__ ei) {
    int e = blockIdx.x * blockDim.x + threadIdx.x;
    if (e < NE) atomicAdd(&g_deg[ei[NE + e]], 1);
}

__global__ void k_scan1() {
    __shared__ int s[SCAN_BLK];
    int b = blockIdx.x, t = threadIdx.x;
    int i = b * SCAN_BLK + t;
    int v = (i < NN) ? g_deg[i] : 0;
    s[t] = v;
    __syncthreads();
    for (int o = 1; o < SCAN_BLK; o <<= 1) {
        int u = (t >= o) ? s[t - o] : 0;
        __syncthreads();
        s[t] += u;
        __syncthreads();
    }
    if (i < NN) g_tmp[i] = s[t];
    if (t == SCAN_BLK - 1) g_bsum[b] = s[t];
}

__global__ void k_scan2() {
    __shared__ int s[128];
    int t = threadIdx.x;
    int v = (t < NB_SCAN) ? g_bsum[t] : 0;
    s[t] = v;
    __syncthreads();
    for (int o = 1; o < 128; o <<= 1) {
        int u = (t >= o) ? s[t - o] : 0;
        __syncthreads();
        s[t] += u;
        __syncthreads();
    }
    if (t < NB_SCAN) g_bpre[t] = s[t] - v;   // exclusive
}

__global__ void k_scan3() {
    int i = blockIdx.x * blockDim.x + threadIdx.x;
    if (i >= NN) return;
    int R = g_tmp[i] + g_bpre[i >> 10];
    g_rowptr[i + 1] = R;
    g_cur[i + 1] = R;
    if (i == 0) { g_rowptr[0] = 0; g_cur[0] = 0; }
}

__global__ void k_scatter(const int* __restrict__ ei) {
    int e = blockIdx.x * blockDim.x + threadIdx.x;
    if (e >= NE) return;
    int s = ei[e], d = ei[NE + e];
    int pos = atomicAdd(&g_cur[d], 1);
    g_srcs[pos] = s;
}

// ---------------- layer 1 node linear: y = x @ W11a (bf16-pair out) ----------------
// 16 nodes per chunk; thread t: node = t>>4, col-pair = t&15 (1 broadcast + 1 float2 per k)
__global__ void k_lin1(const float* __restrict__ x, const float* __restrict__ W) {
    __shared__ float2 sW2[FIN * 16];     // W as pairs: sW2[k*16+l] = (W[k][2l], W[k][2l+1])
    __shared__ float sx[16][FIN];
    for (int j = threadIdx.x; j < FIN * 16; j += blockDim.x)
        sW2[j] = ((const float2*)W)[j];
    int na = threadIdx.x >> 4, l = threadIdx.x & 15;
    for (int c = blockIdx.x; c < NCHUNK; c += gridDim.x) {
        int n0 = c * 16;
        __syncthreads();
        for (int j = threadIdx.x; j < 16 * FIN; j += blockDim.x) {
            int r = j / FIN, k = j - r * FIN;
            sx[r][k] = x[(n0 + r) * FIN + k];
        }
        __syncthreads();
        float a0 = 0.f, a1 = 0.f;
        #pragma unroll
        for (int k = 0; k < FIN; ++k) {
            float xv = sx[na][k];
            float2 w = sW2[k * 16 + l];
            a0 += xv * w.x; a1 += xv * w.y;
        }
        g_y16[(n0 + na) * 16 + l] = packbf(a0, a1);
    }
}

// gather chunk: 8 independent row fetches (uint = bf16 pair at lane's col-pair l)
#define GATHER8U(SRCARR, A0, A1, P, E, L)                                      \
    for (; P + 8 <= E; P += 8) {                                               \
        int s0 = g_srcs[P], s1 = g_srcs[P + 1], s2 = g_srcs[P + 2],            \
            s3 = g_srcs[P + 3], s4 = g_srcs[P + 4], s5 = g_srcs[P + 5],        \
            s6 = g_srcs[P + 6], s7 = g_srcs[P + 7];                            \
        uint v0 = SRCARR[s0 * 16 + L], v1 = SRCARR[s1 * 16 + L];               \
        uint v2 = SRCARR[s2 * 16 + L], v3 = SRCARR[s3 * 16 + L];               \
        uint v4 = SRCARR[s4 * 16 + L], v5 = SRCARR[s5 * 16 + L];               \
        uint v6 = SRCARR[s6 * 16 + L], v7 = SRCARR[s7 * 16 + L];               \
        A0 += lo2f(v0) + lo2f(v1) + lo2f(v2) + lo2f(v3)                        \
            + lo2f(v4) + lo2f(v5) + lo2f(v6) + lo2f(v7);                       \
        A1 += hi2f(v0) + hi2f(v1) + hi2f(v2) + hi2f(v3)                        \
            + hi2f(v4) + hi2f(v5) + hi2f(v6) + hi2f(v7);                       \
    }                                                                          \
    for (; P < E; ++P) {                                                       \
        uint v = SRCARR[g_srcs[P] * 16 + L];                                   \
        A0 += lo2f(v); A1 += hi2f(v);                                          \
    }

// BN block reduction: thread t holds (ls0,lq0) for feature 2*(t&15), (ls1,lq1) for 2*(t&15)+1
#define BN_REDUCE16()                                                          \
    do {                                                                       \
        __syncthreads();                                                       \
        sred[0][threadIdx.x] = ls0; sred[1][threadIdx.x] = lq0;                \
        sred[2][threadIdx.x] = ls1; sred[3][threadIdx.x] = lq1;                \
        __syncthreads();                                                       \
        if (threadIdx.x < 16) {                                                \
            float S0 = 0, Q0 = 0, S1 = 0, Q1 = 0;                              \
            for (int j = 0; j < 16; ++j) {                                     \
                S0 += sred[0][threadIdx.x + 16 * j];                           \
                Q0 += sred[1][threadIdx.x + 16 * j];                           \
                S1 += sred[2][threadIdx.x + 16 * j];                           \
                Q1 += sred[3][threadIdx.x + 16 * j];                           \
            }                                                                  \
            atomicAdd(&g_sum[2 * threadIdx.x], S0);                            \
            atomicAdd(&g_sq[2 * threadIdx.x], Q0);                             \
            atomicAdd(&g_sum[2 * threadIdx.x + 1], S1);                        \
            atomicAdd(&g_sq[2 * threadIdx.x + 1], Q1);                         \
        }                                                                      \
    } while (0)

// layer 1: gather y, z1 = elu(relu(agg+ba) @ Wb + bb) -> g_za. Quarter-wave per node.
__global__ void k_gp1(const float* __restrict__ ba, const float* __restrict__ Wb,
                      const float* __restrict__ bb) {
    __shared__ float2 sW2[DD * 16];
    __shared__ float sba[DD], sbb[DD];
    __shared__ float srow[16][DD + 1];
    __shared__ float sred[4][256];
    for (int j = threadIdx.x; j < DD * 16; j += blockDim.x) sW2[j] = ((const float2*)Wb)[j];
    if (threadIdx.x < DD) { sba[threadIdx.x] = ba[threadIdx.x]; sbb[threadIdx.x] = bb[threadIdx.x]; }
    __syncthreads();
    int q = threadIdx.x >> 4, l = threadIdx.x & 15;
    float ls0 = 0, lq0 = 0, ls1 = 0, lq1 = 0;
    for (int c = blockIdx.x; c < NCHUNK; c += gridDim.x) {
        int n = c * 16 + q;
        uint self = g_y16[n * 16 + l];
        float a0 = lo2f(self), a1 = hi2f(self);
        int p = g_rowptr[n], e = g_rowptr[n + 1];
        GATHER8U(g_y16, a0, a1, p, e, l)
        a0 = fmaxf(a0 + sba[2 * l], 0.f);
        a1 = fmaxf(a1 + sba[2 * l + 1], 0.f);
        srow[q][2 * l] = a0;            // quarter-private row: no barrier needed
        srow[q][2 * l + 1] = a1;
        float z0 = sbb[2 * l], z1 = sbb[2 * l + 1];
        #pragma unroll
        for (int k = 0; k < DD; ++k) {
            float xv = srow[q][k];
            float2 w = sW2[k * 16 + l];
            z0 += xv * w.x; z1 += xv * w.y;
        }
        z0 = (z0 > 0.f) ? z0 : (__expf(z0) - 1.f);
        z1 = (z1 > 0.f) ? z1 : (__expf(z1) - 1.f);
        g_za[n * 16 + l] = packbf(z0, z1);
        ls0 += z0; lq0 += z0 * z0; ls1 += z1; lq1 += z1 * z1;
    }
    BN_REDUCE16();
}

// layers 2/3: gather raw z; v = agg_z @ Wp - (deg+1)*c + ba; u=relu(v); z'=relu(u @ Wb + bb)
template <int DIR>
__global__ void k_gp2(const float* __restrict__ ba, const float* __restrict__ Wb,
                      const float* __restrict__ bb) {
    __shared__ float2 sWp2[DD * 16];
    __shared__ float2 sW2[DD * 16];
    __shared__ float sc[DD], sba[DD], sbb[DD];
    __shared__ float srow[16][DD + 1];
    __shared__ float srow2[16][DD + 1];
    __shared__ float sred[4][256];
    for (int j = threadIdx.x; j < DD * 16; j += blockDim.x) {
        sWp2[j] = ((const float2*)g_Wp)[j];
        sW2[j] = ((const float2*)Wb)[j];
    }
    if (threadIdx.x < DD) {
        sc[threadIdx.x] = g_c[threadIdx.x];
        sba[threadIdx.x] = ba[threadIdx.x];
        sbb[threadIdx.x] = bb[threadIdx.x];
    }
    __syncthreads();
    const uint* zin = (DIR == 0) ? g_za : g_zb;
    uint* zout      = (DIR == 0) ? g_zb : g_za;
    int q = threadIdx.x >> 4, l = threadIdx.x & 15;
    float ls0 = 0, lq0 = 0, ls1 = 0, lq1 = 0;
    for (int c = blockIdx.x; c < NCHUNK; c += gridDim.x) {
        int n = c * 16 + q;
        uint self = zin[n * 16 + l];
        float a0 = lo2f(self), a1 = hi2f(self);
        int p = g_rowptr[n], e = g_rowptr[n + 1];
        int deg = e - p;
        GATHER8U(zin, a0, a1, p, e, l)
        srow[q][2 * l] = a0;
        srow[q][2 * l + 1] = a1;
        float dp1 = (float)(deg + 1);
        float v0 = sba[2 * l] - dp1 * sc[2 * l];
        float v1 = sba[2 * l + 1] - dp1 * sc[2 * l + 1];
        #pragma unroll
        for (int k = 0; k < DD; ++k) {
            float xv = srow[q][k];
            float2 w = sWp2[k * 16 + l];
            v0 += xv * w.x; v1 += xv * w.y;
        }
        srow2[q][2 * l] = fmaxf(v0, 0.f);
        srow2[q][2 * l + 1] = fmaxf(v1, 0.f);
        float z0 = sbb[2 * l], z1 = sbb[2 * l + 1];
        #pragma unroll
        for (int k = 0; k < DD; ++k) {
            float xv = srow2[q][k];
            float2 w = sW2[k * 16 + l];
            z0 += xv * w.x; z1 += xv * w.y;
        }
        z0 = fmaxf(z0, 0.f);
        z1 = fmaxf(z1, 0.f);
        zout[n * 16 + l] = packbf(z0, z1);
        ls0 += z0; lq0 += z0 * z0; ls1 += z1; lq1 += z1 * z1;
    }
    BN_REDUCE16();
}

// Finalize BN stats; if NEXT, fold into next layer's weight (Wp, c). Re-zero accumulators.
template <bool NEXT>
__global__ void k_fold(const float* __restrict__ Wn) {
    __shared__ float sm[DD], sinv[DD], sWp[DD * DD];
    int t = threadIdx.x;
    if (t < DD) {
        float m = g_sum[t] * (1.f / NN);
        float v = g_sq[t] * (1.f / NN) - m * m;
        float iv = rsqrtf(v + BN_EPS);
        sm[t] = m; sinv[t] = iv;
        g_m[t] = m; g_inv[t] = iv;
        g_sum[t] = 0.f; g_sq[t] = 0.f;
    }
    __syncthreads();
    if (NEXT) {
        for (int j = t; j < DD * DD; j += blockDim.x) {
            int k = j >> 5;
            float w = sinv[k] * Wn[j];
            sWp[j] = w;
            g_Wp[j] = w;
        }
        __syncthreads();
        if (t < DD) {
            float c = 0.f;
            #pragma unroll
            for (int k = 0; k < DD; ++k) c += sm[k] * sWp[k * DD + t];
            g_c[t] = c;
        }
    }
}

__global__ void k_tstats(const float* __restrict__ target, const float* __restrict__ g1) {
    __shared__ float ssum[256], ssq[256];
    int f = blockIdx.x, t = threadIdx.x;
    float ls = 0.f, lq = 0.f;
    for (int b = t; b < NG; b += 256) { float v = target[b * TD + f]; ls += v; lq += v * v; }
    ssum[t] = ls; ssq[t] = lq;
    __syncthreads();
    for (int s = 128; s >= 1; s >>= 1) {
        if (t < s) { ssum[t] += ssum[t + s]; ssq[t] += ssq[t + s]; }
        __syncthreads();
    }
    if (t == 0) {
        float m = ssum[0] * (1.f / NG);
        float v = ssq[0] * (1.f / NG) - m * m;
        g_tm[f] = m;
        g_ta[f] = rsqrtf(v + BN_EPS) * g1[f];
    }
}

// Per-graph fused: pool(z3 range) -> BN-fold -> Wn2 -> g (write out_g), then
// BN(target)->W31->W32->softmax, concat, W4->relu, W5->sigmoid -> out.
__global__ void k_graph(const int* __restrict__ batch,
                        const float* __restrict__ Wn2, const float* __restrict__ bn2b,
                        const float* __restrict__ target, const float* __restrict__ be1,
                        const float* __restrict__ W31, const float* __restrict__ b31,
                        const float* __restrict__ W32, const float* __restrict__ b32,
                        const float* __restrict__ W4, const float* __restrict__ b4,
                        const float* __restrict__ W5, const float* __restrict__ b5,
                        float* __restrict__ out, float* __restrict__ out_g) {
    __shared__ float sp[8][DD + 1];
    __shared__ float sh[DD];
    __shared__ int bnd[2];
    __shared__ float tbn[TD];
    __shared__ float t1[H1];
    __shared__ float gl[H2];
    __shared__ float smx[H2];
    __shared__ float xr[H2];
    __shared__ float red[128];
    int b = blockIdx.x, t = threadIdx.x;
    if (t < 2) {
        int key = b + t;
        int lo = 0, hi = NN;
        while (lo < hi) { int mid = (lo + hi) >> 1; if (batch[mid] < key) lo = mid + 1; else hi = mid; }
        bnd[t] = lo;
    }
    for (int j = t; j < TD; j += 256)
        tbn[j] = (target[b * TD + j] - g_tm[j]) * g_ta[j] + be1[j];
    __syncthreads();
    int s0 = bnd[0], s1 = bnd[1];
    int r = t >> 5, f = t & 31;
    {
        const bf16* za16 = (const bf16*)g_za;
        float acc = 0.f;
        for (int n = s0 + r; n < s1; n += 8) acc += b2f(za16[n * DD + f]);
        sp[r][f] = acc;
    }
    __syncthreads();
    if (t < DD) {
        float tot = 0.f;
        #pragma unroll
        for (int j = 0; j < 8; ++j) tot += sp[j][t];
        sh[t] = g_inv[t] * (tot - (float)(s1 - s0) * g_m[t]);
    }
    if (t < H1) {
        float acc = b31[t];
        for (int k = 0; k < TD; ++k) acc += tbn[k] * W31[k * H1 + t];
        t1[t] = acc;
    }
    __syncthreads();
    float tv = 0.f;
    if (t < H2) {
        float a2 = bn2b[t];
        #pragma unroll
        for (int k = 0; k < DD; ++k) a2 += sh[k] * Wn2[k * H2 + t];
        a2 = fmaxf(a2, 0.f);
        gl[t] = a2;
        out_g[b * H2 + t] = a2;
        float acc = b32[t];
        for (int j = 0; j < H1; ++j) acc += t1[j] * W32[j * H2 + t];
        tv = acc;
        red[t] = tv;
    }
    __syncthreads();
    for (int s = 64; s >= 1; s >>= 1) { if (t < s) red[t] = fmaxf(red[t], red[t + s]); __syncthreads(); }
    float mx = red[0];
    __syncthreads();
    float ex = 0.f;
    if (t < H2) { ex = __expf(tv - mx); red[t] = ex; }
    __syncthreads();
    for (int s = 64; s >= 1; s >>= 1) { if (t < s) red[t] += red[t + s]; __syncthreads(); }
    float isum = 1.f / red[0];
    __syncthreads();
    if (t < H2) smx[t] = ex * isum;
    __syncthreads();
    if (t < H2) {
        float acc = b4[t];
        #pragma unroll 4
        for (int i = 0; i < H2; ++i)
            acc += gl[i] * W4[i * H2 + t] + smx[i] * W4[(H2 + i) * H2 + t];
        xr[t] = fmaxf(acc, 0.f);
    }
    __syncthreads();
    if (t < H2) red[t] = xr[t] * W5[t];
    __syncthreads();
    for (int s = 64; s >= 1; s >>= 1) { if (t < s) red[t] += red[t + s]; __syncthreads(); }
    if (t == 0) out[b] = 1.f / (1.f + __expf(-(red[0] + b5[0])));
}

extern "C" void kernel_launch(void* const* d_in, const int* in_sizes, int n_in,
                              void* d_out, int out_size, void* d_ws, size_t ws_size,
                              hipStream_t stream) {
    const float* x      = (const float*)d_in[0];
    const int*   ei     = (const int*)d_in[1];
    const int*   batch  = (const int*)d_in[2];
    const float* target = (const float*)d_in[3];
    const float* W11a = (const float*)d_in[4];
    const float* b11a = (const float*)d_in[5];
    const float* W11b = (const float*)d_in[6];
    const float* b11b = (const float*)d_in[7];
    const float* W12a = (const float*)d_in[8];
    const float* b12a = (const float*)d_in[9];
    const float* W12b = (const float*)d_in[10];
    const float* b12b = (const float*)d_in[11];
    const float* W13a = (const float*)d_in[12];
    const float* b13a = (const float*)d_in[13];
    const float* W13b = (const float*)d_in[14];
    const float* b13b = (const float*)d_in[15];
    const float* Wn2  = (const float*)d_in[16];
    const float* bn2b = (const float*)d_in[17];
    const float* g1   = (const float*)d_in[18];
    const float* be1  = (const float*)d_in[19];
    const float* W31  = (const float*)d_in[20];
    const float* b31  = (const float*)d_in[21];
    const float* W32  = (const float*)d_in[22];
    const float* b32  = (const float*)d_in[23];
    const float* W4   = (const float*)d_in[24];
    const float* b4   = (const float*)d_in[25];
    const float* W5   = (const float*)d_in[26];
    const float* b5   = (const float*)d_in[27];
    float* out   = (float*)d_out;
    float* out_g = out + NG;

    // --- CSR build (by dst) ---
    k_zero<<<256, 256, 0, stream>>>();
    k_hist<<<(NE + 255) / 256, 256, 0, stream>>>(ei);
    k_scan1<<<NB_SCAN, SCAN_BLK, 0, stream>>>();
    k_scan2<<<1, 128, 0, stream>>>();
    k_scan3<<<(NN + 255) / 256, 256, 0, stream>>>();
    k_scatter<<<(NE + 255) / 256, 256, 0, stream>>>(ei);

    // --- layer 1 ---
    k_lin1<<<2048, 256, 0, stream>>>(x, W11a);
    k_gp1<<<2048, 256, 0, stream>>>(b11a, W11b, b11b);
    k_fold<true><<<1, 256, 0, stream>>>(W12a);

    // --- layer 2 (za -> zb) ---
    k_gp2<0><<<2048, 256, 0, stream>>>(b12a, W12b, b12b);
    k_fold<true><<<1, 256, 0, stream>>>(W13a);

    // --- layer 3 (zb -> za) ---
    k_gp2<1><<<2048, 256, 0, stream>>>(b13a, W13b, b13b);
    k_fold<false><<<1, 256, 0, stream>>>(nullptr);

    // --- head ---
    k_tstats<<<TD, 256, 0, stream>>>(target, g1);
    k_graph<<<NG, 256, 0, stream>>>(batch, Wn2, bn2b, target, be1,
                                    W31, b31, W32, b32, W4, b4, W5, b5, out, out_g);
}

// Round 6
// 747.471 us; speedup vs baseline: 1.1244x; 1.1244x over previous
//
#include <hip/hip_runtime.h>
#include <hip/hip_bf16.h>
#include <math.h>

#define NN 100000
#define NE 1000000
#define NG 2048
#define FIN 78
#define DD 32
#define TD 208
#define H1 170
#define H2 128
#define BN_EPS 1e-5f
#define SCAN_BLK 1024
#define NB_SCAN ((NN + SCAN_BLK - 1) / SCAN_BLK)   // 98

// ---- static device workspace (module memory; fully rewritten every call) ----
// Feature arrays have NN+1 rows: row NN is an all-zero row used as the target
// of masked (past-end) gather loads.
__device__ float g_y[(NN + 1) * DD];   // layer-1 pre-agg features (x @ W11a)
__device__ float g_za[(NN + 1) * DD];  // z ping buffer (layer1 out, layer3 out)
__device__ float g_zb[(NN + 1) * DD];  // z pong buffer (layer2 out)
__device__ float g_sum[DD];            // BN stat accumulators
__device__ float g_sq[DD];
__device__ float g_m[DD];              // BN mean / inv-std of last computed layer
__device__ float g_inv[DD];
__device__ float g_Wp[DD * DD];        // BN-folded next-layer weight: diag(inv) @ W
__device__ float g_c[DD];              // (m*inv) @ W  (subtract per node per (deg+1))
__device__ float g_tm[TD];             // target BN mean
__device__ float g_ta[TD];             // target BN inv*gamma
// CSR-by-dst build
__device__ int g_deg[NN];
__device__ int g_tmp[NN];
__device__ int g_bsum[NB_SCAN];
__device__ int g_bpre[NB_SCAN];
__device__ int g_rowptr[NN + 1];
__device__ int g_cur[NN + 1];
__device__ int g_srcs[NE];

__global__ void k_zero() {
    int i = blockIdx.x * blockDim.x + threadIdx.x;
    int stride = gridDim.x * blockDim.x;
    for (int j = i; j < NN; j += stride) g_deg[j] = 0;
    if (i < DD) {
        g_sum[i] = 0.f; g_sq[i] = 0.f;
        g_y[NN * DD + i] = 0.f;    // zero rows for masked gathers
        g_za[NN * DD + i] = 0.f;
        g_zb[NN * DD + i] = 0.f;
    }
}

// ---------------- CSR build (by destination) ----------------
__global__ void k_hist(const int* __restrict__ ei) {
    int e = blockIdx.x * blockDim.x + threadIdx.x;
    if (e < NE) atomicAdd(&g_deg[ei[NE + e]], 1);
}

__global__ void k_scan1() {
    __shared__ int s[SCAN_BLK];
    int b = blockIdx.x, t = threadIdx.x;
    int i = b * SCAN_BLK + t;
    int v = (i < NN) ? g_deg[i] : 0;
    s[t] = v;
    __syncthreads();
    for (int o = 1; o < SCAN_BLK; o <<= 1) {
        int u = (t >= o) ? s[t - o] : 0;
        __syncthreads();
        s[t] += u;
        __syncthreads();
    }
    if (i < NN) g_tmp[i] = s[t];
    if (t == SCAN_BLK - 1) g_bsum[b] = s[t];
}

__global__ void k_scan2() {
    __shared__ int s[128];
    int t = threadIdx.x;
    int v = (t < NB_SCAN) ? g_bsum[t] : 0;
    s[t] = v;
    __syncthreads();
    for (int o = 1; o < 128; o <<= 1) {
        int u = (t >= o) ? s[t - o] : 0;
        __syncthreads();
        s[t] += u;
        __syncthreads();
    }
    if (t < NB_SCAN) g_bpre[t] = s[t] - v;   // exclusive
}

__global__ void k_scan3() {
    int i = blockIdx.x * blockDim.x + threadIdx.x;
    if (i >= NN) return;
    int R = g_tmp[i] + g_bpre[i >> 10];
    g_rowptr[i + 1] = R;
    g_cur[i + 1] = R;
    if (i == 0) { g_rowptr[0] = 0; g_cur[0] = 0; }
}

__global__ void k_scatter(const int* __restrict__ ei) {
    int e = blockIdx.x * blockDim.x + threadIdx.x;
    if (e >= NE) return;
    int s = ei[e], d = ei[NE + e];
    int pos = atomicAdd(&g_cur[d], 1);
    g_srcs[pos] = s;
}

// ---------------- layer 1 node linear: y = x @ W11a ----------------
__global__ void k_lin1(const float* __restrict__ x, const float* __restrict__ W) {
    __shared__ float sW[FIN * DD];
    __shared__ float sx[8][FIN];
    for (int j = threadIdx.x; j < FIN * DD; j += blockDim.x) sW[j] = W[j];
    int nl = threadIdx.x >> 5, f = threadIdx.x & 31;
    const int nchunk = (NN + 7) / 8;
    for (int c = blockIdx.x; c < nchunk; c += gridDim.x) {
        int n0 = c * 8;
        __syncthreads();
        for (int j = threadIdx.x; j < 8 * FIN; j += blockDim.x) {
            int r = j / FIN, k = j - r * FIN;
            int n = n0 + r;
            sx[r][k] = (n < NN) ? x[n * FIN + k] : 0.f;
        }
        __syncthreads();
        int n = n0 + nl;
        if (n < NN) {
            float acc = 0.f;
            #pragma unroll
            for (int k = 0; k < FIN; ++k) acc += sx[nl][k] * sW[k * DD + f];
            g_y[n * DD + f] = acc;
        }
    }
}

// block-level BN stat reduction helper body (expects sred[256])
#define BN_REDUCE(ls, lq)                                                      \
    do {                                                                       \
        __syncthreads();                                                       \
        sred[threadIdx.x] = (ls);                                              \
        __syncthreads();                                                       \
        for (int s_ = 128; s_ >= 32; s_ >>= 1) {                               \
            if (threadIdx.x < s_) sred[threadIdx.x] += sred[threadIdx.x + s_]; \
            __syncthreads();                                                   \
        }                                                                      \
        if (threadIdx.x < 32) atomicAdd(&g_sum[threadIdx.x & 31], sred[threadIdx.x]);\
        __syncthreads();                                                       \
        sred[threadIdx.x] = (lq);                                              \
        __syncthreads();                                                       \
        for (int s_ = 128; s_ >= 32; s_ >>= 1) {                               \
            if (threadIdx.x < s_) sred[threadIdx.x] += sred[threadIdx.x + s_]; \
            __syncthreads();                                                   \
        }                                                                      \
        if (threadIdx.x < 32) atomicAdd(&g_sq[threadIdx.x & 31], sred[threadIdx.x]);\
    } while (0)

// masked 8-deep gather step: always issues 8 independent row loads; indices past
// the row end are redirected to the zero row (index NN). Clamp keeps srcs reads
// in-bounds.
#define G8(ARR, ACC, P, E)                                                     \
    {                                                                          \
        int b0 = (P), b1 = (P) + 1, b2 = (P) + 2, b3 = (P) + 3;                \
        int b4 = (P) + 4, b5 = (P) + 5, b6 = (P) + 6, b7 = (P) + 7;            \
        int i0 = g_srcs[b0 < NE ? b0 : NE - 1];                                \
        int i1 = g_srcs[b1 < NE ? b1 : NE - 1];                                \
        int i2 = g_srcs[b2 < NE ? b2 : NE - 1];                                \
        int i3 = g_srcs[b3 < NE ? b3 : NE - 1];                                \
        int i4 = g_srcs[b4 < NE ? b4 : NE - 1];                                \
        int i5 = g_srcs[b5 < NE ? b5 : NE - 1];                                \
        int i6 = g_srcs[b6 < NE ? b6 : NE - 1];                                \
        int i7 = g_srcs[b7 < NE ? b7 : NE - 1];                                \
        i0 = (b0 < (E)) ? i0 : NN;  i1 = (b1 < (E)) ? i1 : NN;                 \
        i2 = (b2 < (E)) ? i2 : NN;  i3 = (b3 < (E)) ? i3 : NN;                 \
        i4 = (b4 < (E)) ? i4 : NN;  i5 = (b5 < (E)) ? i5 : NN;                 \
        i6 = (b6 < (E)) ? i6 : NN;  i7 = (b7 < (E)) ? i7 : NN;                 \
        float v0 = ARR[i0 * DD + f], v1 = ARR[i1 * DD + f];                    \
        float v2 = ARR[i2 * DD + f], v3 = ARR[i3 * DD + f];                    \
        float v4 = ARR[i4 * DD + f], v5 = ARR[i5 * DD + f];                    \
        float v6 = ARR[i6 * DD + f], v7 = ARR[i7 * DD + f];                    \
        ACC += ((v0 + v1) + (v2 + v3)) + ((v4 + v5) + (v6 + v7));              \
    }

// layer 1: agg = y_i + sum y_src; z1 = elu(relu(agg+ba) @ Wb + bb) -> g_za
// Half-wave (32 lanes) processes TWO nodes with interleaved masked-8 gathers
// (16 row-loads in flight per half-wave).
__global__ void k_gp1(const float* __restrict__ ba, const float* __restrict__ Wb,
                      const float* __restrict__ bb) {
    __shared__ float sW[DD * DD];
    __shared__ float sba[DD], sbb[DD];
    __shared__ float srow[16][DD];
    __shared__ float sred[256];
    for (int j = threadIdx.x; j < DD * DD; j += blockDim.x) sW[j] = Wb[j];
    if (threadIdx.x < DD) { sba[threadIdx.x] = ba[threadIdx.x]; sbb[threadIdx.x] = bb[threadIdx.x]; }
    __syncthreads();
    int h = threadIdx.x >> 5, f = threadIdx.x & 31;
    float ls = 0.f, lq = 0.f;
    const int nchunk = NN / 16;   // 6250
    for (int c = blockIdx.x; c < nchunk; c += gridDim.x) {
        int nA = c * 16 + h;
        int nB = nA + 8;
        float aA = g_y[nA * DD + f];
        float aB = g_y[nB * DD + f];
        int pA = g_rowptr[nA], eA = g_rowptr[nA + 1];
        int pB = g_rowptr[nB], eB = g_rowptr[nB + 1];
        while (pA < eA || pB < eB) {
            G8(g_y, aA, pA, eA)
            G8(g_y, aB, pB, eB)
            pA += 8; pB += 8;
        }
        aA = fmaxf(aA + sba[f], 0.f);
        aB = fmaxf(aB + sba[f], 0.f);
        srow[h][f] = aA;        // half-wave-private rows: no barrier needed
        srow[8 + h][f] = aB;
        float zA = sbb[f], zB = sbb[f];
        #pragma unroll
        for (int k = 0; k < DD; ++k) {
            float w = sW[k * DD + f];
            zA += srow[h][k] * w;
            zB += srow[8 + h][k] * w;
        }
        zA = (zA > 0.f) ? zA : (__expf(zA) - 1.f);
        zB = (zB > 0.f) ? zB : (__expf(zB) - 1.f);
        g_za[nA * DD + f] = zA;
        g_za[nB * DD + f] = zB;
        ls += zA + zB; lq += zA * zA + zB * zB;
    }
    BN_REDUCE(ls, lq);
}

// layers 2/3: agg_z = z_i + sum z_src; v = agg_z @ Wp - (deg+1)*c + ba;
// u = relu(v); z' = relu(u @ Wb + bb). DIR=0: za->zb. DIR=1: zb->za.
template <int DIR>
__global__ void k_gp2(const float* __restrict__ ba, const float* __restrict__ Wb,
                      const float* __restrict__ bb) {
    __shared__ float sWp[DD * DD];
    __shared__ float sW[DD * DD];
    __shared__ float sc[DD], sba[DD], sbb[DD];
    __shared__ float srow[16][DD];
    __shared__ float srow2[16][DD];
    __shared__ float sred[256];
    for (int j = threadIdx.x; j < DD * DD; j += blockDim.x) { sWp[j] = g_Wp[j]; sW[j] = Wb[j]; }
    if (threadIdx.x < DD) {
        sc[threadIdx.x] = g_c[threadIdx.x];
        sba[threadIdx.x] = ba[threadIdx.x];
        sbb[threadIdx.x] = bb[threadIdx.x];
    }
    __syncthreads();
    const float* zin = (DIR == 0) ? g_za : g_zb;
    float* zout      = (DIR == 0) ? g_zb : g_za;
    int h = threadIdx.x >> 5, f = threadIdx.x & 31;
    float ls = 0.f, lq = 0.f;
    const int nchunk = NN / 16;
    for (int c = blockIdx.x; c < nchunk; c += gridDim.x) {
        int nA = c * 16 + h;
        int nB = nA + 8;
        float aA = zin[nA * DD + f];
        float aB = zin[nB * DD + f];
        int pA = g_rowptr[nA], eA = g_rowptr[nA + 1];
        int pB = g_rowptr[nB], eB = g_rowptr[nB + 1];
        float dA = (float)(eA - pA + 1), dB = (float)(eB - pB + 1);
        while (pA < eA || pB < eB) {
            G8(zin, aA, pA, eA)
            G8(zin, aB, pB, eB)
            pA += 8; pB += 8;
        }
        srow[h][f] = aA;
        srow[8 + h][f] = aB;
        float vA = sba[f] - dA * sc[f];
        float vB = sba[f] - dB * sc[f];
        #pragma unroll
        for (int k = 0; k < DD; ++k) {
            float w = sWp[k * DD + f];
            vA += srow[h][k] * w;
            vB += srow[8 + h][k] * w;
        }
        srow2[h][f] = fmaxf(vA, 0.f);
        srow2[8 + h][f] = fmaxf(vB, 0.f);
        float zA = sbb[f], zB = sbb[f];
        #pragma unroll
        for (int k = 0; k < DD; ++k) {
            float w = sW[k * DD + f];
            zA += srow2[h][k] * w;
            zB += srow2[8 + h][k] * w;
        }
        zA = fmaxf(zA, 0.f);
        zB = fmaxf(zB, 0.f);
        zout[nA * DD + f] = zA;
        zout[nB * DD + f] = zB;
        ls += zA + zB; lq += zA * zA + zB * zB;
    }
    BN_REDUCE(ls, lq);
}

// Finalize BN stats; if NEXT, fold into next layer's weight (Wp, c). Re-zero accumulators.
template <bool NEXT>
__global__ void k_fold(const float* __restrict__ Wn) {
    __shared__ float sm[DD], sinv[DD], sWp[DD * DD];
    int t = threadIdx.x;
    if (t < DD) {
        float m = g_sum[t] * (1.f / NN);
        float v = g_sq[t] * (1.f / NN) - m * m;
        float iv = rsqrtf(v + BN_EPS);
        sm[t] = m; sinv[t] = iv;
        g_m[t] = m; g_inv[t] = iv;
        g_sum[t] = 0.f; g_sq[t] = 0.f;
    }
    __syncthreads();
    if (NEXT) {
        for (int j = t; j < DD * DD; j += blockDim.x) {
            int k = j >> 5;
            float w = sinv[k] * Wn[j];
            sWp[j] = w;
            g_Wp[j] = w;
        }
        __syncthreads();
        if (t < DD) {
            float c = 0.f;
            #pragma unroll
            for (int k = 0; k < DD; ++k) c += sm[k] * sWp[k * DD + t];
            g_c[t] = c;
        }
    }
}

__global__ void k_tstats(const float* __restrict__ target, const float* __restrict__ g1) {
    __shared__ float ssum[256], ssq[256];
    int f = blockIdx.x, t = threadIdx.x;
    float ls = 0.f, lq = 0.f;
    for (int b = t; b < NG; b += 256) { float v = target[b * TD + f]; ls += v; lq += v * v; }
    ssum[t] = ls; ssq[t] = lq;
    __syncthreads();
    for (int s = 128; s >= 1; s >>= 1) {
        if (t < s) { ssum[t] += ssum[t + s]; ssq[t] += ssq[t + s]; }
        __syncthreads();
    }
    if (t == 0) {
        float m = ssum[0] * (1.f / NG);
        float v = ssq[0] * (1.f / NG) - m * m;
        g_tm[f] = m;
        g_ta[f] = rsqrtf(v + BN_EPS) * g1[f];
    }
}

// Per-graph fused: pool(z3 range) -> BN-fold -> Wn2 -> g (write out_g), then
// BN(target)->W31->W32->softmax, concat, W4->relu, W5->sigmoid -> out.
__global__ void k_graph(const int* __restrict__ batch,
                        const float* __restrict__ Wn2, const float* __restrict__ bn2b,
                        const float* __restrict__ target, const float* __restrict__ be1,
                        const float* __restrict__ W31, const float* __restrict__ b31,
                        const float* __restrict__ W32, const float* __restrict__ b32,
                        const float* __restrict__ W4, const float* __restrict__ b4,
                        const float* __restrict__ W5, const float* __restrict__ b5,
                        float* __restrict__ out, float* __restrict__ out_g) {
    __shared__ float sp[8][DD + 1];
    __shared__ float sh[DD];
    __shared__ int bnd[2];
    __shared__ float tbn[TD];
    __shared__ float t1[H1];
    __shared__ float gl[H2];
    __shared__ float smx[H2];
    __shared__ float xr[H2];
    __shared__ float red[128];
    int b = blockIdx.x, t = threadIdx.x;
    if (t < 2) {
        int key = b + t;
        int lo = 0, hi = NN;
        while (lo < hi) { int mid = (lo + hi) >> 1; if (batch[mid] < key) lo = mid + 1; else hi = mid; }
        bnd[t] = lo;
    }
    for (int j = t; j < TD; j += 256)
        tbn[j] = (target[b * TD + j] - g_tm[j]) * g_ta[j] + be1[j];
    __syncthreads();
    int s0 = bnd[0], s1 = bnd[1];
    int r = t >> 5, f = t & 31;
    {
        float acc = 0.f;
        for (int n = s0 + r; n < s1; n += 8) acc += g_za[n * DD + f];
        sp[r][f] = acc;
    }
    __syncthreads();
    if (t < DD) {
        float tot = 0.f;
        #pragma unroll
        for (int j = 0; j < 8; ++j) tot += sp[j][t];
        sh[t] = g_inv[t] * (tot - (float)(s1 - s0) * g_m[t]);
    }
    if (t < H1) {
        float acc = b31[t];
        for (int k = 0; k < TD; ++k) acc += tbn[k] * W31[k * H1 + t];
        t1[t] = acc;
    }
    __syncthreads();
    float tv = 0.f;
    if (t < H2) {
        float a2 = bn2b[t];
        #pragma unroll
        for (int k = 0; k < DD; ++k) a2 += sh[k] * Wn2[k * H2 + t];
        a2 = fmaxf(a2, 0.f);
        gl[t] = a2;
        out_g[b * H2 + t] = a2;
        float acc = b32[t];
        for (int j = 0; j < H1; ++j) acc += t1[j] * W32[j * H2 + t];
        tv = acc;
        red[t] = tv;
    }
    __syncthreads();
    for (int s = 64; s >= 1; s >>= 1) { if (t < s) red[t] = fmaxf(red[t], red[t + s]); __syncthreads(); }
    float mx = red[0];
    __syncthreads();
    float ex = 0.f;
    if (t < H2) { ex = __expf(tv - mx); red[t] = ex; }
    __syncthreads();
    for (int s = 64; s >= 1; s >>= 1) { if (t < s) red[t] += red[t + s]; __syncthreads(); }
    float isum = 1.f / red[0];
    __syncthreads();
    if (t < H2) smx[t] = ex * isum;
    __syncthreads();
    if (t < H2) {
        float acc = b4[t];
        #pragma unroll 4
        for (int i = 0; i < H2; ++i)
            acc += gl[i] * W4[i * H2 + t] + smx[i] * W4[(H2 + i) * H2 + t];
        xr[t] = fmaxf(acc, 0.f);
    }
    __syncthreads();
    if (t < H2) red[t] = xr[t] * W5[t];
    __syncthreads();
    for (int s = 64; s >= 1; s >>= 1) { if (t < s) red[t] += red[t + s]; __syncthreads(); }
    if (t == 0) out[b] = 1.f / (1.f + __expf(-(red[0] + b5[0])));
}

extern "C" void kernel_launch(void* const* d_in, const int* in_sizes, int n_in,
                              void* d_out, int out_size, void* d_ws, size_t ws_size,
                              hipStream_t stream) {
    const float* x      = (const float*)d_in[0];
    const int*   ei     = (const int*)d_in[1];
    const int*   batch  = (const int*)d_in[2];
    const float* target = (const float*)d_in[3];
    const float* W11a = (const float*)d_in[4];
    const float* b11a = (const float*)d_in[5];
    const float* W11b = (const float*)d_in[6];
    const float* b11b = (const float*)d_in[7];
    const float* W12a = (const float*)d_in[8];
    const float* b12a = (const float*)d_in[9];
    const float* W12b = (const float*)d_in[10];
    const float* b12b = (const float*)d_in[11];
    const float* W13a = (const float*)d_in[12];
    const float* b13a = (const float*)d_in[13];
    const float* W13b = (const float*)d_in[14];
    const float* b13b = (const float*)d_in[15];
    const float* Wn2  = (const float*)d_in[16];
    const float* bn2b = (const float*)d_in[17];
    const float* g1   = (const float*)d_in[18];
    const float* be1  = (const float*)d_in[19];
    const float* W31  = (const float*)d_in[20];
    const float* b31  = (const float*)d_in[21];
    const float* W32  = (const float*)d_in[22];
    const float* b32  = (const float*)d_in[23];
    const float* W4   = (const float*)d_in[24];
    const float* b4   = (const float*)d_in[25];
    const float* W5   = (const float*)d_in[26];
    const float* b5   = (const float*)d_in[27];
    float* out   = (float*)d_out;
    float* out_g = out + NG;

    // --- CSR build (by dst) ---
    k_zero<<<256, 256, 0, stream>>>();
    k_hist<<<(NE + 255) / 256, 256, 0, stream>>>(ei);
    k_scan1<<<NB_SCAN, SCAN_BLK, 0, stream>>>();
    k_scan2<<<1, 128, 0, stream>>>();
    k_scan3<<<(NN + 255) / 256, 256, 0, stream>>>();
    k_scatter<<<(NE + 255) / 256, 256, 0, stream>>>(ei);

    // --- layer 1 ---
    k_lin1<<<2048, 256, 0, stream>>>(x, W11a);
    k_gp1<<<3125, 256, 0, stream>>>(b11a, W11b, b11b);
    k_fold<true><<<1, 256, 0, stream>>>(W12a);

    // --- layer 2 (za -> zb) ---
    k_gp2<0><<<3125, 256, 0, stream>>>(b12a, W12b, b12b);
    k_fold<true><<<1, 256, 0, stream>>>(W13a);

    // --- layer 3 (zb -> za) ---
    k_gp2<1><<<3125, 256, 0, stream>>>(b13a, W13b, b13b);
    k_fold<false><<<1, 256, 0, stream>>>(nullptr);

    // --- head ---
    k_tstats<<<TD, 256, 0, stream>>>(target, g1);
    k_graph<<<NG, 256, 0, stream>>>(batch, Wn2, bn2b, target, be1,
                                    W31, b31, W32, b32, W4, b4, W5, b5, out, out_g);
}